// Round 6
// baseline (270.844 us; speedup 1.0000x reference)
//
#include <hip/hip_runtime.h>
#include <hip/hip_bf16.h>
#include <stdint.h>

// GCN: out = relu(adj @ (x @ W) + b)
// x:[32,1024,128] f32, adj:[32,1024,1024] f32, W:[128,128] f32, b:[128] f32
// k1: ST[b][h][m] = (x@W)^T bf16.
// k2 (R6): DRAM-page-friendly. Each block stages 32 FULL adj rows (4KB page
//   each) contiguously -> bf16 into 64KB LDS (one activate per page, vs 16
//   in all prior variants), ONE barrier, then 32 k-chunks of MFMA with the
//   B operand (ST, L2/L3-resident) loaded direct-to-register (16B/lane).

typedef short bf16x8 __attribute__((ext_vector_type(8)));
typedef float f32x4 __attribute__((ext_vector_type(4)));
typedef unsigned short u16x4 __attribute__((ext_vector_type(4)));

__device__ __forceinline__ unsigned short f2bf(float f) {
    uint32_t u = __builtin_bit_cast(uint32_t, f);
    u += 0x7FFFu + ((u >> 16) & 1u);   // RTNE
    return (unsigned short)(u >> 16);
}

// ---------------- k1: ST[b][h][m] = sum_f W[f][h] * x[b][m][f] ----------------
#define K1S 136
__global__ __launch_bounds__(256) void k1_support(const float* __restrict__ x,
                                                  const float* __restrict__ W,
                                                  unsigned short* __restrict__ ST) {
    __shared__ __align__(16) unsigned short xt[64 * K1S];   // [m][f] bf16
    __shared__ __align__(16) unsigned short wt[128 * K1S];  // [h][f] bf16 (W^T)
    int t = threadIdx.x;
    int node_base = blockIdx.x * 64;

    const f32x4* xg = (const f32x4*)(x + (size_t)node_base * 128);
#pragma unroll
    for (int i = 0; i < 8; ++i) {
        int f4 = i * 256 + t;
        int row = f4 >> 5, c4 = f4 & 31;
        f32x4 v = xg[f4];
        u16x4 p;
        p.x = f2bf(v.x); p.y = f2bf(v.y); p.z = f2bf(v.z); p.w = f2bf(v.w);
        *(u16x4*)&xt[row * K1S + c4 * 4] = p;
    }
#pragma unroll
    for (int i = 0; i < 16; ++i) {
        int c = i * 256 + t;
        int f = c >> 5, h4 = c & 31;
        f32x4 v = *(const f32x4*)(W + f * 128 + h4 * 4);
        wt[(h4 * 4 + 0) * K1S + f] = f2bf(v.x);
        wt[(h4 * 4 + 1) * K1S + f] = f2bf(v.y);
        wt[(h4 * 4 + 2) * K1S + f] = f2bf(v.z);
        wt[(h4 * 4 + 3) * K1S + f] = f2bf(v.w);
    }
    __syncthreads();

    int wv = t >> 6, lane = t & 63, l16 = lane & 15, quad = lane >> 4;
    int wave_h = (wv & 1) * 64, wave_m = (wv >> 1) * 32;

    f32x4 acc[4][2];
#pragma unroll
    for (int ht = 0; ht < 4; ++ht)
#pragma unroll
        for (int mt = 0; mt < 2; ++mt) acc[ht][mt] = 0.f;

#pragma unroll
    for (int s = 0; s < 4; ++s) {
        int ko = s * 32 + quad * 8;
        bf16x8 a[4], bb[2];
#pragma unroll
        for (int ht = 0; ht < 4; ++ht)
            a[ht] = *(const bf16x8*)&wt[(wave_h + ht * 16 + l16) * K1S + ko];
#pragma unroll
        for (int mt = 0; mt < 2; ++mt)
            bb[mt] = *(const bf16x8*)&xt[(wave_m + mt * 16 + l16) * K1S + ko];
#pragma unroll
        for (int ht = 0; ht < 4; ++ht)
#pragma unroll
            for (int mt = 0; mt < 2; ++mt)
                acc[ht][mt] = __builtin_amdgcn_mfma_f32_16x16x32_bf16(
                    a[ht], bb[mt], acc[ht][mt], 0, 0, 0);
    }

    int batch = blockIdx.x >> 4;
    int m_in_b = (blockIdx.x & 15) * 64;
#pragma unroll
    for (int ht = 0; ht < 4; ++ht)
#pragma unroll
        for (int mt = 0; mt < 2; ++mt) {
            int mcol = wave_m + mt * 16 + l16;
#pragma unroll
            for (int r = 0; r < 4; ++r) {
                int h = wave_h + ht * 16 + quad * 4 + r;
                ST[(((size_t)batch * 128 + h) << 10) + m_in_b + mcol] =
                    f2bf(acc[ht][mt][r]);
            }
        }
}

// ---------------- k2: out[b][m][n] = relu(sum_k adj[b][m][k]*S[b][k][n] + b[n]) ----
// 1024 blocks: batch = blk>>5, mbase = (blk&31)*32. Stage adj [32m][1024k]
// fully (row-contiguous 4KB reads), bf16 in 64KB LDS with 16B-chunk XOR
// swizzle (chunk c of row r stored at c^(r&7)). One barrier. Then 4 waves
// (16m x 64n each) run 32 kc chunks; B direct from global (ST row = 2KB,
// lane reads 16B at quad*8 + kc*32).
__global__ __launch_bounds__(256) void k2_gcn(const float* __restrict__ adj,
                                              const unsigned short* __restrict__ ST,
                                              const float* __restrict__ bias,
                                              float* __restrict__ out) {
    __shared__ __align__(16) unsigned short As[32 * 1024];  // 64 KiB bf16 [m][k]
    const int t = threadIdx.x;
    const int wv = t >> 6, l = t & 63, l16 = l & 15, quad = l >> 4;
    const int batch = blockIdx.x >> 5;
    const int mbase = (blockIdx.x & 31) * 32;

    const float* adjb = adj + ((size_t)batch * 1024 + mbase) * 1024;

    // --- stage: issue i = adj row i, read contiguously (4KB page, one visit).
    // thread t covers f32 cols [t*4, t*4+3] -> 8B bf16 at chunk c = t>>1,
    // phys chunk = c ^ (i&7), halfword index = i*1024 + phys*8 + (t&1)*4.
    {
        const int c = t >> 1, half = (t & 1) * 4;
#pragma unroll 8
        for (int i = 0; i < 32; ++i) {
            f32x4 v = *(const f32x4*)(adjb + (size_t)i * 1024 + t * 4);
            u16x4 p;
            p.x = f2bf(v.x); p.y = f2bf(v.y); p.z = f2bf(v.z); p.w = f2bf(v.w);
            *(u16x4*)&As[i * 1024 + ((c ^ (i & 7)) << 3) + half] = p;
        }
    }
    __syncthreads();

    const int wave_m = (wv & 1) * 16, wave_n = (wv >> 1) * 64;
    const unsigned short* pB[4];
#pragma unroll
    for (int j = 0; j < 4; ++j)
        pB[j] = ST + ((size_t)(batch * 128 + wave_n + j * 16 + l16)) * 1024 + quad * 8;

    float bv[4];
#pragma unroll
    for (int j = 0; j < 4; ++j) bv[j] = bias[wave_n + j * 16 + l16];

    f32x4 acc[4];
#pragma unroll
    for (int j = 0; j < 4; ++j) acc[j] = 0.f;

    const int ar = wave_m + l16;        // A row within tile (0..31)
    const unsigned short* arow = &As[ar * 1024];
    const int akey = ar & 7;

#pragma unroll 8
    for (int kc = 0; kc < 32; ++kc) {
        bf16x8 a = *(const bf16x8*)&arow[(((kc * 4 + quad) ^ akey) << 3)];
        bf16x8 bb[4];
#pragma unroll
        for (int j = 0; j < 4; ++j)
            bb[j] = *(const bf16x8*)(pB[j] + kc * 32);
#pragma unroll
        for (int j = 0; j < 4; ++j)
            acc[j] = __builtin_amdgcn_mfma_f32_16x16x32_bf16(a, bb[j], acc[j], 0, 0, 0);
    }

    float* outb = out + ((size_t)batch * 1024 + mbase) * 128;
#pragma unroll
    for (int j = 0; j < 4; ++j) {
        int n = wave_n + j * 16 + l16;
#pragma unroll
        for (int r = 0; r < 4; ++r) {
            int m = wave_m + quad * 4 + r;
            float v = acc[j][r] + bv[j];
            outb[(size_t)m * 128 + n] = fmaxf(v, 0.f);
        }
    }
}

extern "C" void kernel_launch(void* const* d_in, const int* in_sizes, int n_in,
                              void* d_out, int out_size, void* d_ws, size_t ws_size,
                              hipStream_t stream) {
    const float* x = (const float*)d_in[0];
    const float* adj = (const float*)d_in[1];
    const float* W = (const float*)d_in[2];
    const float* b = (const float*)d_in[3];
    float* out = (float*)d_out;

    unsigned short* ST = (unsigned short*)d_ws;  // bf16 [32][128][1024] = 8 MiB

    k1_support<<<512, 256, 0, stream>>>(x, W, ST);
    k2_gcn<<<1024, 256, 0, stream>>>(adj, ST, b, out);
}